// Round 16
// baseline (264.701 us; speedup 1.0000x reference)
//
#include <hip/hip_runtime.h>

typedef unsigned short u16;
typedef __attribute__((ext_vector_type(4))) float floatx4;
typedef __attribute__((ext_vector_type(8))) short shortx8;

#define B_ 4
#define S_ 2048
#define D_ 1024
#define H_ 16
#define HD_ 64

__device__ __forceinline__ float b2f(u16 u) {
    return __uint_as_float(((unsigned int)u) << 16);
}
__device__ __forceinline__ u16 f2b(float f) {
    unsigned int u = __float_as_uint(f);
    u += 0x7fffu + ((u >> 16) & 1u);
    return (u16)(u >> 16);
}
__device__ __forceinline__ unsigned long long pack4(float a, float b, float c, float d) {
    return (unsigned long long)f2b(a) | ((unsigned long long)f2b(b) << 16) |
           ((unsigned long long)f2b(c) << 32) | ((unsigned long long)f2b(d) << 48);
}
// bf16x2 pack, round-half-up: (hi16(b+0x8000) << 16) | hi16(a+0x8000) via v_perm_b32
__device__ __forceinline__ unsigned int permpk(float a, float b) {
    return __builtin_amdgcn_perm(__float_as_uint(b) + 0x8000u,
                                 __float_as_uint(a) + 0x8000u, 0x07060302u);
}
// async global->LDS, 16B per lane; LDS dest = wave-uniform base + lane*16
__device__ __forceinline__ void glds16(const u16* g, u16* l) {
    __builtin_amdgcn_global_load_lds(
        (const __attribute__((address_space(1))) unsigned int*)g,
        (__attribute__((address_space(3))) unsigned int*)l, 16, 0, 0);
}
// raw workgroup barrier (no implicit vmcnt/lgkmcnt drain) + compiler fences
__device__ __forceinline__ void bar() {
    asm volatile("" ::: "memory");
    __builtin_amdgcn_s_barrier();
    asm volatile("" ::: "memory");
}
#define VMW4 asm volatile("s_waitcnt vmcnt(4)" ::: "memory")
#define VMW3 asm volatile("s_waitcnt vmcnt(3)" ::: "memory")
#define VMW0 asm volatile("s_waitcnt vmcnt(0)" ::: "memory")

// ---------------------------------------------------------------------------
// Fused preprocessing (one launch):
//   blocks [0,4096):    convert x -> bf16 (block 0: biases + persist flag)
//   blocks [4096,5120): transpose w_attn / w_proj (+ dtype normalize)
//                       in 64x64 tiles -> every output row-write is a FULL
//                       128B line (the old 32x32 tiles wrote 64B half-lines
//                       -> partial-line write amplification, the same
//                       mechanism measured on V^T (r3) and Q/K (r10)).
// Every block self-computes the dtype flag from a 256-sample probe of x.
// ---------------------------------------------------------------------------
__global__ __launch_bounds__(256) void preproc(const void* __restrict__ xin,
                                               u16* __restrict__ xb,
                                               const void* __restrict__ bA,
                                               const void* __restrict__ bP,
                                               u16* __restrict__ bAb,
                                               u16* __restrict__ bPb,
                                               const void* __restrict__ wA,
                                               u16* __restrict__ wtA,
                                               const void* __restrict__ wP,
                                               u16* __restrict__ wtP,
                                               int* __restrict__ flag) {
    __shared__ int cnts[4];
    __shared__ u16 tile[64][65];  // 8.3KB; lane stride 130B -> 2-way (free)
    const int tid = threadIdx.x;
    {
        const unsigned int e = (((const unsigned int*)xin)[tid] >> 7) & 0xffu;
        int c = (e >= 110u && e <= 134u) ? 1 : 0;
#pragma unroll
        for (int d = 1; d < 64; d <<= 1) c += __shfl_xor(c, d);
        if ((tid & 63) == 0) cnts[tid >> 6] = c;
    }
    __syncthreads();
    const int isbf = (cnts[0] + cnts[1] + cnts[2] + cnts[3] > 128) ? 1 : 0;

    const int bid = blockIdx.x;
    if (bid < 4096) {
        // ---- convert x ----
        const size_t i = ((size_t)bid * 256 + tid) * 8;
        if (isbf) {
            *(uint4*)(xb + i) = *(const uint4*)((const u16*)xin + i);
        } else {
            const float* xf = (const float*)xin;
            float4 a = *(const float4*)(xf + i);
            float4 b = *(const float4*)(xf + i + 4);
            u16 o[8] = {f2b(a.x), f2b(a.y), f2b(a.z), f2b(a.w),
                        f2b(b.x), f2b(b.y), f2b(b.z), f2b(b.w)};
            *(uint4*)(xb + i) = *(uint4*)o;
        }
        if (bid == 0) {
            if (tid == 0) *flag = isbf;
            for (int j = tid; j < 3072; j += 256)
                bAb[j] = isbf ? ((const u16*)bA)[j] : f2b(((const float*)bA)[j]);
            for (int j = tid; j < 1024; j += 256)
                bPb[j] = isbf ? ((const u16*)bP)[j] : f2b(((const float*)bP)[j]);
        }
    } else {
        // ---- transpose weights, 64x64 tiles ----
        const int idx = bid - 4096;          // [0, 1024)
        int bxi = idx & 63;                  // N-tile (48 for wA + 16 for wP)
        const int by = (idx >> 6) * 64;      // K index
        const void* in;
        u16* out;
        int N;
        if (bxi < 48) { in = wA; out = wtA; N = 3072; }
        else          { in = wP; out = wtP; N = 1024; bxi -= 48; }
        const int K = 1024;
        const int bx = bxi * 64;
        const int tx = tid & 63;
        const int ty = tid >> 6;
        if (isbf) {
#pragma unroll
            for (int i = 0; i < 64; i += 4)
                tile[ty + i][tx] = ((const u16*)in)[(size_t)(by + ty + i) * N + bx + tx];
        } else {
#pragma unroll
            for (int i = 0; i < 64; i += 4)
                tile[ty + i][tx] = f2b(((const float*)in)[(size_t)(by + ty + i) * N + bx + tx]);
        }
        __syncthreads();
#pragma unroll
        for (int i = 0; i < 64; i += 4)
            out[(size_t)(bx + ty + i) * K + by + tx] = tile[tx][ty + i];
    }
}

// ---------------------------------------------------------------------------
// QKV GEMM: C[M x N] = A[M x K] * BT[N x K]^T + bias.  bf16 in, fp32 accum.
// 256x128 tile, 8 waves (512 thr), 16 waves/CU; LDS 72KB = 3 x (A 16KB +
// B 8KB); 3-buffer counted-vmcnt pipeline; XCD-chunked 1D grid; nb-inner
// scatter epilogues.  Unchanged this round.
// QKV scatter: Q (pre-scaled 0.125*log2e), K -> [bh][s][64];
//              V -> TRANSPOSED [bh][d][s] via LDS-coalesced epilogue.
// ---------------------------------------------------------------------------
__global__ __launch_bounds__(512) void gemm_qkv(const u16* __restrict__ A,
                                                const u16* __restrict__ BT,
                                                const u16* __restrict__ bias,
                                                int M, int N, int K,
                                                u16* __restrict__ qws,
                                                u16* __restrict__ kws,
                                                u16* __restrict__ vws) {
    // 72KB: As buf b at [b*8192, +8192); Bs buf b at [24576 + b*4096, +4096)
    __shared__ __align__(16) u16 lds[36864];

    const int tid = threadIdx.x;
    const int w = tid >> 6, l = tid & 63;
    const int lane_m = l & 15, quad = l >> 4;
    const int bid = blockIdx.x;
    const int bm = ((bid & 7) * 4 + ((bid >> 3) & 3)) * 256;
    const int bn = (bid >> 5) * 128;
    const int wm = (w >> 1) * 64, wn = (w & 1) * 64;

    floatx4 acc[4][4];
#pragma unroll
    for (int i = 0; i < 4; i++)
#pragma unroll
        for (int j = 0; j < 4; j++) acc[i][j] = (floatx4){0.f, 0.f, 0.f, 0.f};

    // staging geometry: lane -> (row-in-unit lr, slot sl); unit = 16 rows
    const int lr = l >> 2, sl = l & 3;
    const int cA = sl ^ ((lr >> 1) & 3);  // logical chunk landing in slot sl
    const int ra0 = w * 32, ra1 = w * 32 + 16, rb = w * 16;
    const u16* Arow0 = A + (size_t)(bm + ra0 + lr) * K + cA * 8;
    const u16* Arow1 = A + (size_t)(bm + ra1 + lr) * K + cA * 8;
    const u16* Brow  = BT + (size_t)(bn + rb + lr) * K + cA * 8;

    auto stage = [&](int t) {
        const int k0 = t * 32;
        u16* ad = lds + (t % 3) * 8192;
        u16* bd = lds + 24576 + (t % 3) * 4096;
        glds16(Arow0 + k0, ad + ra0 * 32);
        glds16(Arow1 + k0, ad + ra1 * 32);
        glds16(Brow + k0, bd + rb * 32);
    };

    const int NT = K >> 5;
    stage(0);
    stage(1);
    for (int t = 0; t < NT; ++t) {
        if (t < NT - 1) { VMW3; } else { VMW0; }  // own stage(t) retired
        bar();              // all waves gated -> tile t resident; WAR-safe
        if (t + 2 < NT) stage(t + 2);

        const u16* Ac = lds + (t % 3) * 8192;
        const u16* Bc = lds + 24576 + (t % 3) * 4096;
        shortx8 af[4], bf[4];
#pragma unroll
        for (int mb = 0; mb < 4; mb++) {
            const int r = wm + mb * 16 + lane_m;
            af[mb] = *(const shortx8*)(Ac + r * 32 + (quad ^ ((r >> 1) & 3)) * 8);
        }
#pragma unroll
        for (int nb = 0; nb < 4; nb++) {
            const int r = wn + nb * 16 + lane_m;
            bf[nb] = *(const shortx8*)(Bc + r * 32 + (quad ^ ((r >> 1) & 3)) * 8);
        }
#pragma unroll
        for (int mb = 0; mb < 4; mb++)
#pragma unroll
            for (int nb = 0; nb < 4; nb++)
                acc[mb][nb] = __builtin_amdgcn_mfma_f32_16x16x32_bf16(
                    af[mb], bf[nb], acc[mb][nb], 0, 0, 0);
    }

    const float SCALE_Q = 0.18033688011112042f;  // 0.125 * log2(e)

    if ((bn >> 10) == 2) {
        // ---- V: LDS-coalesced transposed write ----
        __syncthreads();  // all waves' final frag reads done; LDS reusable
        u16* ep = lds + w * 4096;  // per-wave 8KB scratch
#pragma unroll
        for (int nb = 0; nb < 4; nb++) {
            const int lhd = nb * 16 + lane_m;  // 0..63
            const float bv = b2f(bias[bn + wn + lhd]);
            const int sw = (lhd & 7) << 3;
#pragma unroll
            for (int mb = 0; mb < 4; mb++) {
                const int o = mb * 16 + quad * 4;  // s-local, multiple of 4
                unsigned long long pk =
                    pack4(acc[mb][nb][0] + bv, acc[mb][nb][1] + bv,
                          acc[mb][nb][2] + bv, acc[mb][nb][3] + bv);
                *(unsigned long long*)(ep + lhd * 64 + (o ^ sw)) = pk;
            }
        }
        __syncthreads();
        const int bI = bm >> 11;
        const int hI = ((bn + wn) >> 6) & 15;
        const int s0 = (bm & 2047) + wm;  // multiple of 64 -> 128B aligned
        u16* vb0 = vws + (size_t)(bI * 16 + hI) * 64 * 2048;
        const int rr8 = l >> 3, c8 = l & 7;
#pragma unroll
        for (int p = 0; p < 8; p++) {
            const int lhd = p * 8 + rr8;
            uint4 v4 = *(const uint4*)(ep + lhd * 64 + ((c8 << 3) ^ ((lhd & 7) << 3)));
            *(uint4*)(vb0 + (size_t)lhd * 2048 + s0 + c8 * 8) = v4;
        }
    } else {
        // ---- Q/K scatter, nb-INNER: each (s) line completed in 4 stores ----
        const int which = bn >> 10;  // block-uniform (0=Q, 1=K)
        u16* dst = (which == 0) ? qws : kws;
        const int h = ((bn + wn) >> 6) & 15;   // (bn+wn) is a multiple of 64
        const int bI = bm >> 11;               // block-uniform (bm mult of 256)
        u16* dbase = dst + (size_t)(bI * 16 + h) * 2048 * 64 + lane_m;
        float bv4[4];
#pragma unroll
        for (int nb = 0; nb < 4; nb++) bv4[nb] = b2f(bias[bn + wn + nb * 16 + lane_m]);
#pragma unroll
        for (int mb = 0; mb < 4; mb++) {
#pragma unroll
            for (int r = 0; r < 4; r++) {
                const int s = (bm & 2047) + wm + mb * 16 + quad * 4 + r;
                u16* line = dbase + (size_t)s * 64;
#pragma unroll
                for (int nb = 0; nb < 4; nb++) {
                    float v = acc[mb][nb][r] + bv4[nb];
                    if (which == 0) v *= SCALE_Q;
                    line[nb * 16] = f2b(v);
                }
            }
        }
    }
}

// ---------------------------------------------------------------------------
// PROJ GEMM: 128x128 tile, 4 waves (256 thr), 3-buffer counted-vmcnt
// pipeline (the r7-proven body).  THIS ROUND: the 256-tile proj grid was
// only 256 blocks = 1 block/CU -> no co-resident block to overlap the
// per-iteration gate/barrier stalls (r10's mechanism).  128^2 -> grid
// 64x8 = 512 blocks = 2 blocks/CU (48KB LDS, fits 3).  XCD-chunked:
// bm_tile = (bid&7)*8 + ((bid>>3)&7) in [0,64), bn_tile = bid>>6.
// nb-inner epilogue (full-line completion).
// ---------------------------------------------------------------------------
__global__ __launch_bounds__(256) void gemm_proj(const u16* __restrict__ A,
                                                 const u16* __restrict__ BT,
                                                 const u16* __restrict__ bias,
                                                 void* __restrict__ outv,
                                                 int M, int N, int K,
                                                 const int* __restrict__ flag) {
    __shared__ __align__(16) u16 As[3][128 * 32];  // 3 x 8KB
    __shared__ __align__(16) u16 Bs[3][128 * 32];  // 3 x 8KB

    const int isbf = *flag;
    const int tid = threadIdx.x;
    const int w = tid >> 6, l = tid & 63;
    const int lane_m = l & 15, quad = l >> 4;
    const int bid = blockIdx.x;
    const int bm = ((bid & 7) * 8 + ((bid >> 3) & 7)) * 128;
    const int bn = (bid >> 6) * 128;
    const int wm = (w >> 1) * 64, wn = (w & 1) * 64;

    floatx4 acc[4][4];
#pragma unroll
    for (int i = 0; i < 4; i++)
#pragma unroll
        for (int j = 0; j < 4; j++) acc[i][j] = (floatx4){0.f, 0.f, 0.f, 0.f};

    // staging geometry: wave covers 16-row groups rb0, rb1; lane -> (row, slot)
    const int lr = l >> 2, sl = l & 3;
    const int cA = sl ^ ((lr >> 1) & 3);  // logical chunk that lands in slot sl
    const int rb0 = w * 16, rb1 = 64 + w * 16;
    const u16* Arow0 = A + (size_t)(bm + rb0 + lr) * K + cA * 8;
    const u16* Arow1 = A + (size_t)(bm + rb1 + lr) * K + cA * 8;
    const u16* Brow0 = BT + (size_t)(bn + rb0 + lr) * K + cA * 8;
    const u16* Brow1 = BT + (size_t)(bn + rb1 + lr) * K + cA * 8;

    auto stage = [&](int t) {
        const int k0 = t * 32;
        u16* ad = &As[t % 3][0];
        u16* bd = &Bs[t % 3][0];
        glds16(Arow0 + k0, ad + rb0 * 32);
        glds16(Arow1 + k0, ad + rb1 * 32);
        glds16(Brow0 + k0, bd + rb0 * 32);
        glds16(Brow1 + k0, bd + rb1 * 32);
    };

    const int NT = K >> 5;
    stage(0);
    stage(1);
    for (int t = 0; t < NT; ++t) {
        if (t < NT - 1) { VMW4; } else { VMW0; }  // own stage(t) retired
        bar();              // all waves gated -> tile t resident; WAR-safe
        if (t + 2 < NT) stage(t + 2);

        const u16* Ac = &As[t % 3][0];
        const u16* Bc = &Bs[t % 3][0];
        shortx8 af[4], bf[4];
#pragma unroll
        for (int mb = 0; mb < 4; mb++) {
            const int r = wm + mb * 16 + lane_m;
            af[mb] = *(const shortx8*)(Ac + r * 32 + (quad ^ ((r >> 1) & 3)) * 8);
        }
#pragma unroll
        for (int nb = 0; nb < 4; nb++) {
            const int r = wn + nb * 16 + lane_m;
            bf[nb] = *(const shortx8*)(Bc + r * 32 + (quad ^ ((r >> 1) & 3)) * 8);
        }
#pragma unroll
        for (int mb = 0; mb < 4; mb++)
#pragma unroll
            for (int nb = 0; nb < 4; nb++)
                acc[mb][nb] = __builtin_amdgcn_mfma_f32_16x16x32_bf16(
                    af[mb], bf[nb], acc[mb][nb], 0, 0, 0);
    }

    // ---- store, nb-INNER (full-line completion) ----
    float bv4[4];
#pragma unroll
    for (int nb = 0; nb < 4; nb++) bv4[nb] = b2f(bias[bn + wn + nb * 16 + lane_m]);
#pragma unroll
    for (int mb = 0; mb < 4; mb++) {
#pragma unroll
        for (int r = 0; r < 4; r++) {
            const int rr = bm + wm + mb * 16 + quad * 4 + r;
#pragma unroll
            for (int nb = 0; nb < 4; nb++) {
                const int col = bn + wn + nb * 16 + lane_m;
                float v = acc[mb][nb][r] + bv4[nb];
                if (isbf) ((u16*)outv)[(size_t)rr * N + col] = f2b(v);
                else ((float*)outv)[(size_t)rr * N + col] = v;
            }
        }
    }
}

// ---------------------------------------------------------------------------
// Flash attention, causal, transposed-score, WORK-BALANCED 2-pass,
// 8 waves x 16 q-rows, XCD-chunked 1D grid of 512 (measured-optimal:
// 2-pass/512 beats 16-row split (r5), 3-block grids (r14), cross-tile
// pipelining (r12), counted-vmcnt gates (r7)).  Unchanged this round.
// S^T = K*Q^T (col=q,row=kv) -> in-register softmax; O^T = V^T*P^T.
// + defer-max (T13, THR=8) and s_setprio around MFMA clusters (T5).
// ---------------------------------------------------------------------------
__global__ __launch_bounds__(512, 4) void attn_kernel(const u16* __restrict__ Qg,
                                                      const u16* __restrict__ Kg,
                                                      const u16* __restrict__ Vtg,
                                                      u16* __restrict__ Og) {
    __shared__ __align__(16) u16 Ks[2][64 * 64];  // K tile [kv][d], swizzled
    __shared__ __align__(16) u16 Vs[2][64 * 64];  // V^T tile [d][kv], swizzled
    __shared__ __align__(16) u16 Ps[8][16 * 72];  // per-wave P^T as [q][kv]

    const int tid = threadIdx.x, w = tid >> 6, l = tid & 63;
    const int lane_m = l & 15, quad = l >> 4;
    // T1 XCD-chunked swizzle: same-head blocks -> same XCD
    const int bid = blockIdx.x;
    const int bh = (bid & 7) * 8 + ((bid >> 3) >> 3);
    const int xmi = (bid >> 3) & 7;
    const u16* qp = Qg + (size_t)bh * S_ * 64;
    const u16* kp = Kg + (size_t)bh * S_ * 64;
    const u16* vtp = Vtg + (size_t)bh * 64 * S_;
    u16* psw = &Ps[w][0];
    const int b = bh >> 4, h = bh & 15;

    // staging geometry: 8 rows per wave (8 waves cover 64); lane->(row,slot)
    const int lr8 = l >> 3, sl8 = l & 7;
    const int cK = sl8 ^ (lr8 & 7);  // logical chunk landing in slot sl8
    const int rbase = w * 8;
    const u16* Kr = kp + (size_t)(rbase + lr8) * 64 + cK * 8;
    const u16* Vr = vtp + (size_t)(rbase + lr8) * S_ + cK * 8;  // rows = d

    auto stage = [&](int t) {
        const int k0 = t * 64;
        glds16(Kr + (size_t)k0 * 64, &Ks[t & 1][0] + rbase * 64);
        glds16(Vr + k0, &Vs[t & 1][0] + rbase * 64);
    };

    for (int pass = 0; pass < 2; pass++) {
        const int xm = pass ? (15 - xmi) : xmi;
        const int q0 = xm * 128;
        const int qw0 = q0 + w * 16;  // this wave's 16 q-rows

        shortx8 qF[2];
#pragma unroll
        for (int ks = 0; ks < 2; ks++)
            qF[ks] = *(const shortx8*)(qp + (size_t)(qw0 + lane_m) * 64 + ks * 32 + quad * 8);

        floatx4 o_acc[4];
#pragma unroll
        for (int md = 0; md < 4; md++) o_acc[md] = (floatx4){0.f, 0.f, 0.f, 0.f};
        float m_i = -1e30f, l_i = 0.f;

        const int ntiles = (q0 >> 6) + 2;
        const int myend = qw0 + 15;

        __syncthreads();  // pass seam: prior pass's LDS reads complete
        stage(0);
        for (int t = 0; t < ntiles; t++) {
            const int k0 = t * 64;
            __syncthreads();  // buf[t&1] DMA drained; reads of buf[(t+1)&1] done
            if (t + 1 < ntiles) stage(t + 1);

            if (k0 <= myend) {  // wave-uniform: skip fully-masked tiles
                const u16* kb = &Ks[t & 1][0];
                const u16* vb = &Vs[t & 1][0];
                // ---- S^T = K * Q^T ----
                floatx4 sc[4];
#pragma unroll
                for (int mb = 0; mb < 4; mb++) sc[mb] = (floatx4){0.f, 0.f, 0.f, 0.f};
#pragma unroll
                for (int ks = 0; ks < 2; ks++) {
                    shortx8 kA[4];
#pragma unroll
                    for (int mb = 0; mb < 4; mb++) {
                        const int r = mb * 16 + lane_m;
                        kA[mb] = *(const shortx8*)(kb + r * 64 + (((ks * 4 + quad) ^ (r & 7)) * 8));
                    }
                    __builtin_amdgcn_s_setprio(1);
#pragma unroll
                    for (int mb = 0; mb < 4; mb++)
                        sc[mb] = __builtin_amdgcn_mfma_f32_16x16x32_bf16(
                            kA[mb], qF[ks], sc[mb], 0, 0, 0);
                    __builtin_amdgcn_s_setprio(0);
                }

                const int qg = qw0 + lane_m;
                if (k0 + 63 > qw0) {  // partially masked tile
#pragma unroll
                    for (int mb = 0; mb < 4; mb++)
#pragma unroll
                        for (int r = 0; r < 4; r++) {
                            const int kvg = k0 + mb * 16 + quad * 4 + r;
                            if (kvg > qg) sc[mb][r] = -1e30f;
                        }
                }
                float mloc = -1e30f;
#pragma unroll
                for (int mb = 0; mb < 4; mb++) {
                    float a = fmaxf(fmaxf(sc[mb][0], sc[mb][1]),
                                    fmaxf(sc[mb][2], sc[mb][3]));
                    mloc = fmaxf(mloc, a);
                }
                mloc = fmaxf(mloc, __shfl_xor(mloc, 16));
                mloc = fmaxf(mloc, __shfl_xor(mloc, 32));
                // defer-max (T13): if no lane's max grew by >8, keep m_old;
                // P bounded by 2^8 (safe in bf16/fp32 accum), rescale skipped.
                float mnew = m_i;
                if (!__all(mloc <= m_i + 8.0f)) {
                    mnew = fmaxf(m_i, mloc);
                    const float alpha = __builtin_amdgcn_exp2f(m_i - mnew);
                    m_i = mnew;
                    l_i *= alpha;
#pragma unroll
                    for (int md = 0; md < 4; md++) o_acc[md] *= alpha;
                }
                float psum = 0.f;
#pragma unroll
                for (int mb = 0; mb < 4; mb++) {
                    const float p0 = __builtin_amdgcn_exp2f(sc[mb][0] - mnew);
                    const float p1 = __builtin_amdgcn_exp2f(sc[mb][1] - mnew);
                    const float p2 = __builtin_amdgcn_exp2f(sc[mb][2] - mnew);
                    const float p3 = __builtin_amdgcn_exp2f(sc[mb][3] - mnew);
                    psum += (p0 + p1) + (p2 + p3);
                    // P^T [q][kv]: 4 consecutive kv -> one 8B write (perm pack)
                    uint2 pk = {permpk(p0, p1), permpk(p2, p3)};
                    *(uint2*)(psw + lane_m * 72 + mb * 16 + quad * 4) = pk;
                }
                psum += __shfl_xor(psum, 16);
                psum += __shfl_xor(psum, 32);
                l_i += psum;
                // no barrier: Ps region is per-wave

                // ---- O^T += V^T * P^T ----
#pragma unroll
                for (int ks = 0; ks < 2; ks++) {
                    shortx8 vF[4], pF;
#pragma unroll
                    for (int md = 0; md < 4; md++) {
                        const int r = md * 16 + lane_m;
                        vF[md] = *(const shortx8*)(vb + r * 64 + (((ks * 4 + quad) ^ (r & 7)) * 8));
                    }
                    pF = *(const shortx8*)(psw + lane_m * 72 + ks * 32 + quad * 8);
                    __builtin_amdgcn_s_setprio(1);
#pragma unroll
                    for (int md = 0; md < 4; md++)
                        o_acc[md] = __builtin_amdgcn_mfma_f32_16x16x32_bf16(
                            vF[md], pF, o_acc[md], 0, 0, 0);
                    __builtin_amdgcn_s_setprio(0);
                }
            }
        }

        // ---- epilogue: O^T col=q=lane_m, row=d=16md+quad*4+r ----
        {
            const float inv = 1.0f / l_i;
            const int qg = qw0 + lane_m;
            const size_t base = ((size_t)b * 2048 + qg) * 1024 + h * 64;
#pragma unroll
            for (int md = 0; md < 4; md++) {
                *(unsigned long long*)(Og + base + md * 16 + quad * 4) =
                    pack4(o_acc[md][0] * inv, o_acc[md][1] * inv,
                          o_acc[md][2] * inv, o_acc[md][3] * inv);
            }
        }
    }
}

// ---------------------------------------------------------------------------
extern "C" void kernel_launch(void* const* d_in, const int* in_sizes, int n_in,
                              void* d_out, int out_size, void* d_ws, size_t ws_size,
                              hipStream_t stream) {
    const void* x      = d_in[0];
    const void* w_attn = d_in[2];
    const void* b_attn = d_in[3];
    const void* w_proj = d_in[4];
    const void* b_proj = d_in[5];

    u16* qws = (u16*)d_ws;                 // 8388608
    u16* kws = qws + 8388608;
    u16* vws = kws + 8388608;              // holds V^T [bh][d][s]
    u16* xb  = vws + 8388608;              // x normalized to bf16
    u16* aws = xb;                         // attn output aliases xb
    u16* wtA = xb + 8388608;               // w_attn^T: 3072x1024
    u16* wtP = wtA + 3145728;              // w_proj^T: 1024x1024
    u16* bAb = wtP + 1048576;              // 3072
    u16* bPb = bAb + 3072;                 // 1024
    int* flag = (int*)(bPb + 1024);

    preproc<<<5120, 256, 0, stream>>>(x, xb, b_attn, b_proj, bAb, bPb,
                                      w_attn, wtA, w_proj, wtP, flag);

    gemm_qkv<<<dim3(32 * 24), 512, 0, stream>>>(
        xb, wtA, bAb, 8192, 3072, 1024, qws, kws, vws);

    attn_kernel<<<dim3(512), 512, 0, stream>>>(qws, kws, vws, aws);

    gemm_proj<<<dim3(64 * 8), 256, 0, stream>>>(
        aws, wtP, bPb, d_out, 8192, 1024, 1024, flag);
}

// Round 17
// 249.373 us; speedup vs baseline: 1.0615x; 1.0615x over previous
//
#include <hip/hip_runtime.h>

typedef unsigned short u16;
typedef __attribute__((ext_vector_type(4))) float floatx4;
typedef __attribute__((ext_vector_type(8))) short shortx8;

#define B_ 4
#define S_ 2048
#define D_ 1024
#define H_ 16
#define HD_ 64

__device__ __forceinline__ float b2f(u16 u) {
    return __uint_as_float(((unsigned int)u) << 16);
}
__device__ __forceinline__ u16 f2b(float f) {
    unsigned int u = __float_as_uint(f);
    u += 0x7fffu + ((u >> 16) & 1u);
    return (u16)(u >> 16);
}
__device__ __forceinline__ unsigned long long pack4(float a, float b, float c, float d) {
    return (unsigned long long)f2b(a) | ((unsigned long long)f2b(b) << 16) |
           ((unsigned long long)f2b(c) << 32) | ((unsigned long long)f2b(d) << 48);
}
// bf16x2 pack, round-half-up: (hi16(b+0x8000) << 16) | hi16(a+0x8000) via v_perm_b32
__device__ __forceinline__ unsigned int permpk(float a, float b) {
    return __builtin_amdgcn_perm(__float_as_uint(b) + 0x8000u,
                                 __float_as_uint(a) + 0x8000u, 0x07060302u);
}
// async global->LDS, 16B per lane; LDS dest = wave-uniform base + lane*16
__device__ __forceinline__ void glds16(const u16* g, u16* l) {
    __builtin_amdgcn_global_load_lds(
        (const __attribute__((address_space(1))) unsigned int*)g,
        (__attribute__((address_space(3))) unsigned int*)l, 16, 0, 0);
}
// raw workgroup barrier (no implicit vmcnt/lgkmcnt drain) + compiler fences
__device__ __forceinline__ void bar() {
    asm volatile("" ::: "memory");
    __builtin_amdgcn_s_barrier();
    asm volatile("" ::: "memory");
}
#define VMW3 asm volatile("s_waitcnt vmcnt(3)" ::: "memory")
#define VMW0 asm volatile("s_waitcnt vmcnt(0)" ::: "memory")

// ---------------------------------------------------------------------------
// Fused preprocessing (one launch):
//   blocks [0,4096):   convert x -> bf16 (block 0: biases + persist flag)
//   blocks [4096,8192): transpose w_attn / w_proj (+ dtype normalize)
// Every block self-computes the dtype flag from a 256-sample probe of x.
// ---------------------------------------------------------------------------
__global__ __launch_bounds__(256) void preproc(const void* __restrict__ xin,
                                               u16* __restrict__ xb,
                                               const void* __restrict__ bA,
                                               const void* __restrict__ bP,
                                               u16* __restrict__ bAb,
                                               u16* __restrict__ bPb,
                                               const void* __restrict__ wA,
                                               u16* __restrict__ wtA,
                                               const void* __restrict__ wP,
                                               u16* __restrict__ wtP,
                                               int* __restrict__ flag) {
    __shared__ int cnts[4];
    __shared__ u16 tile[32][33];
    const int tid = threadIdx.x;
    {
        const unsigned int e = (((const unsigned int*)xin)[tid] >> 7) & 0xffu;
        int c = (e >= 110u && e <= 134u) ? 1 : 0;
#pragma unroll
        for (int d = 1; d < 64; d <<= 1) c += __shfl_xor(c, d);
        if ((tid & 63) == 0) cnts[tid >> 6] = c;
    }
    __syncthreads();
    const int isbf = (cnts[0] + cnts[1] + cnts[2] + cnts[3] > 128) ? 1 : 0;

    const int bid = blockIdx.x;
    if (bid < 4096) {
        // ---- convert x ----
        const size_t i = ((size_t)bid * 256 + tid) * 8;
        if (isbf) {
            *(uint4*)(xb + i) = *(const uint4*)((const u16*)xin + i);
        } else {
            const float* xf = (const float*)xin;
            float4 a = *(const float4*)(xf + i);
            float4 b = *(const float4*)(xf + i + 4);
            u16 o[8] = {f2b(a.x), f2b(a.y), f2b(a.z), f2b(a.w),
                        f2b(b.x), f2b(b.y), f2b(b.z), f2b(b.w)};
            *(uint4*)(xb + i) = *(uint4*)o;
        }
        if (bid == 0) {
            if (tid == 0) *flag = isbf;
            for (int j = tid; j < 3072; j += 256)
                bAb[j] = isbf ? ((const u16*)bA)[j] : f2b(((const float*)bA)[j]);
            for (int j = tid; j < 1024; j += 256)
                bPb[j] = isbf ? ((const u16*)bP)[j] : f2b(((const float*)bP)[j]);
        }
    } else {
        // ---- transpose weights ----
        const int idx = bid - 4096;          // [0, 4096)
        int bxi = idx & 127;                 // N-tile
        const int by = (idx >> 7) * 32;      // K index
        const void* in;
        u16* out;
        int N;
        if (bxi < 96) { in = wA; out = wtA; N = 3072; }
        else          { in = wP; out = wtP; N = 1024; bxi -= 96; }
        const int K = 1024;
        const int bx = bxi * 32;
        const int tx = tid & 31;
        const int ty = tid >> 5;
        if (isbf) {
#pragma unroll
            for (int i = 0; i < 32; i += 8)
                tile[ty + i][tx] = ((const u16*)in)[(size_t)(by + ty + i) * N + bx + tx];
        } else {
#pragma unroll
            for (int i = 0; i < 32; i += 8)
                tile[ty + i][tx] = f2b(((const float*)in)[(size_t)(by + ty + i) * N + bx + tx]);
        }
        __syncthreads();
#pragma unroll
        for (int i = 0; i < 32; i += 8)
            out[(size_t)(bx + ty + i) * K + by + tx] = tile[tx][ty + i];
    }
}

// ---------------------------------------------------------------------------
// C[M x N] = A[M x K] * BT[N x K]^T + bias.  bf16 in, fp32 accum.
// 256x128 tile, 8 waves (512 thr), 16 waves/CU; LDS 72KB = 3 x (A 16KB +
// B 8KB); 3-buffer counted-vmcnt pipeline; XCD-chunked 1D grid; nb-inner
// scatter epilogues (r11: WRITE_SIZE 80 -> ~50MB).
// MODE 0: store to out (bf16 or fp32 per flag).
// MODE 1: QKV scatter: Q (pre-scaled 0.125*log2e), K -> [bh][s][64];
//         V -> TRANSPOSED [bh][d][s] via LDS-coalesced epilogue.
// ---------------------------------------------------------------------------
template <int MODE>
__global__ __launch_bounds__(512) void gemm_bt(const u16* __restrict__ A,
                                               const u16* __restrict__ BT,
                                               const u16* __restrict__ bias,
                                               void* __restrict__ outv,
                                               int M, int N, int K,
                                               u16* __restrict__ qws,
                                               u16* __restrict__ kws,
                                               u16* __restrict__ vws,
                                               const int* __restrict__ flag) {
    // 72KB: As buf b at [b*8192, +8192); Bs buf b at [24576 + b*4096, +4096)
    __shared__ __align__(16) u16 lds[36864];

    const int isbf = (MODE == 0) ? *flag : 1;
    const int tid = threadIdx.x;
    const int w = tid >> 6, l = tid & 63;
    const int lane_m = l & 15, quad = l >> 4;
    const int bid = blockIdx.x;
    const int bm = ((bid & 7) * 4 + ((bid >> 3) & 3)) * 256;
    const int bn = (bid >> 5) * 128;
    const int wm = (w >> 1) * 64, wn = (w & 1) * 64;

    floatx4 acc[4][4];
#pragma unroll
    for (int i = 0; i < 4; i++)
#pragma unroll
        for (int j = 0; j < 4; j++) acc[i][j] = (floatx4){0.f, 0.f, 0.f, 0.f};

    // staging geometry: lane -> (row-in-unit lr, slot sl); unit = 16 rows
    const int lr = l >> 2, sl = l & 3;
    const int cA = sl ^ ((lr >> 1) & 3);  // logical chunk landing in slot sl
    const int ra0 = w * 32, ra1 = w * 32 + 16, rb = w * 16;
    const u16* Arow0 = A + (size_t)(bm + ra0 + lr) * K + cA * 8;
    const u16* Arow1 = A + (size_t)(bm + ra1 + lr) * K + cA * 8;
    const u16* Brow  = BT + (size_t)(bn + rb + lr) * K + cA * 8;

    auto stage = [&](int t) {
        const int k0 = t * 32;
        u16* ad = lds + (t % 3) * 8192;
        u16* bd = lds + 24576 + (t % 3) * 4096;
        glds16(Arow0 + k0, ad + ra0 * 32);
        glds16(Arow1 + k0, ad + ra1 * 32);
        glds16(Brow + k0, bd + rb * 32);
    };

    const int NT = K >> 5;
    stage(0);
    stage(1);
    for (int t = 0; t < NT; ++t) {
        if (t < NT - 1) { VMW3; } else { VMW0; }  // own stage(t) retired
        bar();              // all waves gated -> tile t resident; WAR-safe
        if (t + 2 < NT) stage(t + 2);

        const u16* Ac = lds + (t % 3) * 8192;
        const u16* Bc = lds + 24576 + (t % 3) * 4096;
        shortx8 af[4], bf[4];
#pragma unroll
        for (int mb = 0; mb < 4; mb++) {
            const int r = wm + mb * 16 + lane_m;
            af[mb] = *(const shortx8*)(Ac + r * 32 + (quad ^ ((r >> 1) & 3)) * 8);
        }
#pragma unroll
        for (int nb = 0; nb < 4; nb++) {
            const int r = wn + nb * 16 + lane_m;
            bf[nb] = *(const shortx8*)(Bc + r * 32 + (quad ^ ((r >> 1) & 3)) * 8);
        }
#pragma unroll
        for (int mb = 0; mb < 4; mb++)
#pragma unroll
            for (int nb = 0; nb < 4; nb++)
                acc[mb][nb] = __builtin_amdgcn_mfma_f32_16x16x32_bf16(
                    af[mb], bf[nb], acc[mb][nb], 0, 0, 0);
    }

    const float SCALE_Q = 0.18033688011112042f;  // 0.125 * log2(e)

    if (MODE == 1 && (bn >> 10) == 2) {
        // ---- V: LDS-coalesced transposed write ----
        __syncthreads();  // all waves' final frag reads done; LDS reusable
        u16* ep = lds + w * 4096;  // per-wave 8KB scratch
#pragma unroll
        for (int nb = 0; nb < 4; nb++) {
            const int lhd = nb * 16 + lane_m;  // 0..63
            const float bv = b2f(bias[bn + wn + lhd]);
            const int sw = (lhd & 7) << 3;
#pragma unroll
            for (int mb = 0; mb < 4; mb++) {
                const int o = mb * 16 + quad * 4;  // s-local, multiple of 4
                unsigned long long pk =
                    pack4(acc[mb][nb][0] + bv, acc[mb][nb][1] + bv,
                          acc[mb][nb][2] + bv, acc[mb][nb][3] + bv);
                *(unsigned long long*)(ep + lhd * 64 + (o ^ sw)) = pk;
            }
        }
        __syncthreads();
        const int bI = bm >> 11;
        const int hI = ((bn + wn) >> 6) & 15;
        const int s0 = (bm & 2047) + wm;  // multiple of 64 -> 128B aligned
        u16* vb0 = vws + (size_t)(bI * 16 + hI) * 64 * 2048;
        const int rr8 = l >> 3, c8 = l & 7;
#pragma unroll
        for (int p = 0; p < 8; p++) {
            const int lhd = p * 8 + rr8;
            uint4 v4 = *(const uint4*)(ep + lhd * 64 + ((c8 << 3) ^ ((lhd & 7) << 3)));
            *(uint4*)(vb0 + (size_t)lhd * 2048 + s0 + c8 * 8) = v4;
        }
    } else if (MODE == 1) {
        // ---- Q/K scatter, nb-INNER: each (s) line completed in 4 stores ----
        const int which = bn >> 10;  // block-uniform (0=Q, 1=K)
        u16* dst = (which == 0) ? qws : kws;
        const int h = ((bn + wn) >> 6) & 15;   // (bn+wn) is a multiple of 64
        const int bI = bm >> 11;               // block-uniform (bm mult of 256)
        u16* dbase = dst + (size_t)(bI * 16 + h) * 2048 * 64 + lane_m;
        float bv4[4];
#pragma unroll
        for (int nb = 0; nb < 4; nb++) bv4[nb] = b2f(bias[bn + wn + nb * 16 + lane_m]);
#pragma unroll
        for (int mb = 0; mb < 4; mb++) {
#pragma unroll
            for (int r = 0; r < 4; r++) {
                const int s = (bm & 2047) + wm + mb * 16 + quad * 4 + r;
                u16* line = dbase + (size_t)s * 64;
#pragma unroll
                for (int nb = 0; nb < 4; nb++) {
                    float v = acc[mb][nb][r] + bv4[nb];
                    if (which == 0) v *= SCALE_Q;
                    line[nb * 16] = f2b(v);
                }
            }
        }
    } else {
        // ---- MODE 0 store, nb-INNER (same open-line argument) ----
        float bv4[4];
#pragma unroll
        for (int nb = 0; nb < 4; nb++) bv4[nb] = b2f(bias[bn + wn + nb * 16 + lane_m]);
#pragma unroll
        for (int mb = 0; mb < 4; mb++) {
#pragma unroll
            for (int r = 0; r < 4; r++) {
                const int rr = bm + wm + mb * 16 + quad * 4 + r;
#pragma unroll
                for (int nb = 0; nb < 4; nb++) {
                    const int col = bn + wn + nb * 16 + lane_m;
                    float v = acc[mb][nb][r] + bv4[nb];
                    if (isbf) ((u16*)outv)[(size_t)rr * N + col] = f2b(v);
                    else ((float*)outv)[(size_t)rr * N + col] = v;
                }
            }
        }
    }
}

// ---------------------------------------------------------------------------
// Flash attention, causal, transposed-score, WORK-BALANCED 2-pass,
// 8 waves x 16 q-rows, XCD-chunked 1D grid of 512 (measured-optimal:
// beats 16-row split (r5), 3-block grids (r14), cross-tile pipelining
// (r12), counted-vmcnt gates (r7)).
// S^T = K*Q^T (col=q,row=kv) -> in-register softmax; O^T = V^T*P^T.
// + defer-max (T13, THR=8) and s_setprio around MFMA clusters (T5).
// ---------------------------------------------------------------------------
__global__ __launch_bounds__(512, 4) void attn_kernel(const u16* __restrict__ Qg,
                                                      const u16* __restrict__ Kg,
                                                      const u16* __restrict__ Vtg,
                                                      u16* __restrict__ Og) {
    __shared__ __align__(16) u16 Ks[2][64 * 64];  // K tile [kv][d], swizzled
    __shared__ __align__(16) u16 Vs[2][64 * 64];  // V^T tile [d][kv], swizzled
    __shared__ __align__(16) u16 Ps[8][16 * 72];  // per-wave P^T as [q][kv]

    const int tid = threadIdx.x, w = tid >> 6, l = tid & 63;
    const int lane_m = l & 15, quad = l >> 4;
    // T1 XCD-chunked swizzle: same-head blocks -> same XCD
    const int bid = blockIdx.x;
    const int bh = (bid & 7) * 8 + ((bid >> 3) >> 3);
    const int xmi = (bid >> 3) & 7;
    const u16* qp = Qg + (size_t)bh * S_ * 64;
    const u16* kp = Kg + (size_t)bh * S_ * 64;
    const u16* vtp = Vtg + (size_t)bh * 64 * S_;
    u16* psw = &Ps[w][0];
    const int b = bh >> 4, h = bh & 15;

    // staging geometry: 8 rows per wave (8 waves cover 64); lane->(row,slot)
    const int lr8 = l >> 3, sl8 = l & 7;
    const int cK = sl8 ^ (lr8 & 7);  // logical chunk landing in slot sl8
    const int rbase = w * 8;
    const u16* Kr = kp + (size_t)(rbase + lr8) * 64 + cK * 8;
    const u16* Vr = vtp + (size_t)(rbase + lr8) * S_ + cK * 8;  // rows = d

    auto stage = [&](int t) {
        const int k0 = t * 64;
        glds16(Kr + (size_t)k0 * 64, &Ks[t & 1][0] + rbase * 64);
        glds16(Vr + k0, &Vs[t & 1][0] + rbase * 64);
    };

    for (int pass = 0; pass < 2; pass++) {
        const int xm = pass ? (15 - xmi) : xmi;
        const int q0 = xm * 128;
        const int qw0 = q0 + w * 16;  // this wave's 16 q-rows

        shortx8 qF[2];
#pragma unroll
        for (int ks = 0; ks < 2; ks++)
            qF[ks] = *(const shortx8*)(qp + (size_t)(qw0 + lane_m) * 64 + ks * 32 + quad * 8);

        floatx4 o_acc[4];
#pragma unroll
        for (int md = 0; md < 4; md++) o_acc[md] = (floatx4){0.f, 0.f, 0.f, 0.f};
        float m_i = -1e30f, l_i = 0.f;

        const int ntiles = (q0 >> 6) + 2;
        const int myend = qw0 + 15;

        __syncthreads();  // pass seam: prior pass's LDS reads complete
        stage(0);
        for (int t = 0; t < ntiles; t++) {
            const int k0 = t * 64;
            __syncthreads();  // buf[t&1] DMA drained; reads of buf[(t+1)&1] done
            if (t + 1 < ntiles) stage(t + 1);

            if (k0 <= myend) {  // wave-uniform: skip fully-masked tiles
                const u16* kb = &Ks[t & 1][0];
                const u16* vb = &Vs[t & 1][0];
                // ---- S^T = K * Q^T ----
                floatx4 sc[4];
#pragma unroll
                for (int mb = 0; mb < 4; mb++) sc[mb] = (floatx4){0.f, 0.f, 0.f, 0.f};
#pragma unroll
                for (int ks = 0; ks < 2; ks++) {
                    shortx8 kA[4];
#pragma unroll
                    for (int mb = 0; mb < 4; mb++) {
                        const int r = mb * 16 + lane_m;
                        kA[mb] = *(const shortx8*)(kb + r * 64 + (((ks * 4 + quad) ^ (r & 7)) * 8));
                    }
                    __builtin_amdgcn_s_setprio(1);
#pragma unroll
                    for (int mb = 0; mb < 4; mb++)
                        sc[mb] = __builtin_amdgcn_mfma_f32_16x16x32_bf16(
                            kA[mb], qF[ks], sc[mb], 0, 0, 0);
                    __builtin_amdgcn_s_setprio(0);
                }

                const int qg = qw0 + lane_m;
                if (k0 + 63 > qw0) {  // partially masked tile
#pragma unroll
                    for (int mb = 0; mb < 4; mb++)
#pragma unroll
                        for (int r = 0; r < 4; r++) {
                            const int kvg = k0 + mb * 16 + quad * 4 + r;
                            if (kvg > qg) sc[mb][r] = -1e30f;
                        }
                }
                float mloc = -1e30f;
#pragma unroll
                for (int mb = 0; mb < 4; mb++) {
                    float a = fmaxf(fmaxf(sc[mb][0], sc[mb][1]),
                                    fmaxf(sc[mb][2], sc[mb][3]));
                    mloc = fmaxf(mloc, a);
                }
                mloc = fmaxf(mloc, __shfl_xor(mloc, 16));
                mloc = fmaxf(mloc, __shfl_xor(mloc, 32));
                // defer-max (T13): if no lane's max grew by >8, keep m_old;
                // P bounded by 2^8 (safe in bf16/fp32 accum), rescale skipped.
                float mnew = m_i;
                if (!__all(mloc <= m_i + 8.0f)) {
                    mnew = fmaxf(m_i, mloc);
                    const float alpha = __builtin_amdgcn_exp2f(m_i - mnew);
                    m_i = mnew;
                    l_i *= alpha;
#pragma unroll
                    for (int md = 0; md < 4; md++) o_acc[md] *= alpha;
                }
                float psum = 0.f;
#pragma unroll
                for (int mb = 0; mb < 4; mb++) {
                    const float p0 = __builtin_amdgcn_exp2f(sc[mb][0] - mnew);
                    const float p1 = __builtin_amdgcn_exp2f(sc[mb][1] - mnew);
                    const float p2 = __builtin_amdgcn_exp2f(sc[mb][2] - mnew);
                    const float p3 = __builtin_amdgcn_exp2f(sc[mb][3] - mnew);
                    psum += (p0 + p1) + (p2 + p3);
                    // P^T [q][kv]: 4 consecutive kv -> one 8B write (perm pack)
                    uint2 pk = {permpk(p0, p1), permpk(p2, p3)};
                    *(uint2*)(psw + lane_m * 72 + mb * 16 + quad * 4) = pk;
                }
                psum += __shfl_xor(psum, 16);
                psum += __shfl_xor(psum, 32);
                l_i += psum;
                // no barrier: Ps region is per-wave

                // ---- O^T += V^T * P^T ----
#pragma unroll
                for (int ks = 0; ks < 2; ks++) {
                    shortx8 vF[4], pF;
#pragma unroll
                    for (int md = 0; md < 4; md++) {
                        const int r = md * 16 + lane_m;
                        vF[md] = *(const shortx8*)(vb + r * 64 + (((ks * 4 + quad) ^ (r & 7)) * 8));
                    }
                    pF = *(const shortx8*)(psw + lane_m * 72 + ks * 32 + quad * 8);
                    __builtin_amdgcn_s_setprio(1);
#pragma unroll
                    for (int md = 0; md < 4; md++)
                        o_acc[md] = __builtin_amdgcn_mfma_f32_16x16x32_bf16(
                            vF[md], pF, o_acc[md], 0, 0, 0);
                    __builtin_amdgcn_s_setprio(0);
                }
            }
        }

        // ---- epilogue: O^T col=q=lane_m, row=d=16md+quad*4+r ----
        {
            const float inv = 1.0f / l_i;
            const int qg = qw0 + lane_m;
            const size_t base = ((size_t)b * 2048 + qg) * 1024 + h * 64;
#pragma unroll
            for (int md = 0; md < 4; md++) {
                *(unsigned long long*)(Og + base + md * 16 + quad * 4) =
                    pack4(o_acc[md][0] * inv, o_acc[md][1] * inv,
                          o_acc[md][2] * inv, o_acc[md][3] * inv);
            }
        }
    }
}

// ---------------------------------------------------------------------------
extern "C" void kernel_launch(void* const* d_in, const int* in_sizes, int n_in,
                              void* d_out, int out_size, void* d_ws, size_t ws_size,
                              hipStream_t stream) {
    const void* x      = d_in[0];
    const void* w_attn = d_in[2];
    const void* b_attn = d_in[3];
    const void* w_proj = d_in[4];
    const void* b_proj = d_in[5];

    u16* qws = (u16*)d_ws;                 // 8388608
    u16* kws = qws + 8388608;
    u16* vws = kws + 8388608;              // holds V^T [bh][d][s]
    u16* xb  = vws + 8388608;              // x normalized to bf16
    u16* aws = xb;                         // attn output aliases xb
    u16* wtA = xb + 8388608;               // w_attn^T: 3072x1024
    u16* wtP = wtA + 3145728;              // w_proj^T: 1024x1024
    u16* bAb = wtP + 1048576;              // 3072
    u16* bPb = bAb + 3072;                 // 1024
    int* flag = (int*)(bPb + 1024);

    preproc<<<8192, 256, 0, stream>>>(x, xb, b_attn, b_proj, bAb, bPb,
                                      w_attn, wtA, w_proj, wtP, flag);

    gemm_bt<1><<<dim3(32 * 24), 512, 0, stream>>>(
        xb, wtA, bAb, nullptr, 8192, 3072, 1024, qws, kws, vws, flag);

    attn_kernel<<<dim3(512), 512, 0, stream>>>(qws, kws, vws, aws);

    gemm_bt<0><<<dim3(32 * 8), 512, 0, stream>>>(
        aws, wtP, bPb, d_out, 8192, 1024, 1024, nullptr, nullptr, nullptr, flag);
}